// Round 1
// baseline (308.100 us; speedup 1.0000x reference)
//
#include <hip/hip_runtime.h>
#include <cstdint>

typedef __attribute__((ext_vector_type(8))) short short8;
typedef __attribute__((ext_vector_type(4))) float f32x4;
typedef unsigned short u16t;

// ---------- helpers ----------
__device__ __forceinline__ u16t f2bf(float f) {
  uint32_t u = __float_as_uint(f);
  u += 0x7fffu + ((u >> 16) & 1u);   // RNE
  return (u16t)(u >> 16);
}

__device__ __forceinline__ void gload_lds16(const void* g, void* l) {
  __builtin_amdgcn_global_load_lds(
      (const __attribute__((address_space(1))) void*)g,
      (__attribute__((address_space(3))) void*)l, 16, 0, 0);
}

// ---------- f32 -> bf16 convert ----------
__global__ __launch_bounds__(256) void cvt_bf16_kernel(const float* __restrict__ in,
                                                       u16t* __restrict__ out, int n8) {
  int i = blockIdx.x * 256 + threadIdx.x;
  if (i >= n8) return;
  const float4* p = (const float4*)in + (size_t)i * 2;
  float4 a = p[0], b = p[1];
  union { short8 v; u16t e[8]; } r;
  r.e[0] = f2bf(a.x); r.e[1] = f2bf(a.y); r.e[2] = f2bf(a.z); r.e[3] = f2bf(a.w);
  r.e[4] = f2bf(b.x); r.e[5] = f2bf(b.y); r.e[6] = f2bf(b.z); r.e[7] = f2bf(b.w);
  *((short8*)out + i) = r.v;
}

// ---------- LayerNorm (row = 768 f32) -> bf16 ----------
__global__ __launch_bounds__(256) void ln_kernel(const float* __restrict__ x,
                                                 const float* __restrict__ g,
                                                 const float* __restrict__ b,
                                                 u16t* __restrict__ out) {
  int row = blockIdx.x, tid = threadIdx.x;
  int wave = tid >> 6, lane = tid & 63;
  const float* xr = x + (size_t)row * 768;
  float v0 = xr[tid], v1 = xr[tid + 256], v2 = xr[tid + 512];
  float s = v0 + v1 + v2;
  float q = v0 * v0 + v1 * v1 + v2 * v2;
#pragma unroll
  for (int m = 32; m >= 1; m >>= 1) {
    s += __shfl_xor(s, m, 64);
    q += __shfl_xor(q, m, 64);
  }
  __shared__ float red[8];
  if (lane == 0) { red[wave] = s; red[4 + wave] = q; }
  __syncthreads();
  s = red[0] + red[1] + red[2] + red[3];
  q = red[4] + red[5] + red[6] + red[7];
  float mu = s * (1.0f / 768.0f);
  float var = q * (1.0f / 768.0f) - mu * mu;
  float rs = rsqrtf(var + 1e-5f);
  u16t* orow = out + (size_t)row * 768;
  orow[tid]       = f2bf((v0 - mu) * rs * g[tid]       + b[tid]);
  orow[tid + 256] = f2bf((v1 - mu) * rs * g[tid + 256] + b[tid + 256]);
  orow[tid + 512] = f2bf((v2 - mu) * rs * g[tid + 512] + b[tid + 512]);
}

// ---------- GEMM: C[M,N] = A[M,K] @ W[N,K]^T  (bf16 in, fp32 acc) ----------
// EPI 0: bf16 store of acc
// EPI 1: f32 store of acc + bias[c] + res[r*N+c]
// EPI 2: bf16 store of gelu_exact(acc + bias[c])
template <int EPI>
__global__ __launch_bounds__(256, 2) void gemm_bt(const u16t* __restrict__ A,
                                                  const u16t* __restrict__ W,
                                                  void* __restrict__ Cout,
                                                  const float* __restrict__ bias,
                                                  const float* __restrict__ res,
                                                  int M, int N, int K) {
  __shared__ __align__(16) u16t As[128 * 64];
  __shared__ __align__(16) u16t Bs[128 * 64];
  int tid = threadIdx.x;
  int wave = tid >> 6, lane = tid & 63;
  int wr = wave >> 1, wc = wave & 1;
  int bm = blockIdx.y * 128;
  int bn = blockIdx.x * 128;
  f32x4 acc[4][4] = {};

  int lr = lane >> 3;            // staging row-in-chunk 0..7
  int lc = lane & 7;             // staging 16B slot 0..7
  int srcslot = lc ^ lr;         // inverse-swizzled source slot
  const u16t* Abase = A + (size_t)(bm + lr) * K + srcslot * 8;
  const u16t* Wbase = W + (size_t)(bn + lr) * K + srcslot * 8;

  for (int kt = 0; kt < K; kt += 64) {
    __syncthreads();
#pragma unroll
    for (int i = 0; i < 4; i++) {
      int chunk = wave * 4 + i;  // 16 chunks of 8 rows x 128B
      gload_lds16(Abase + (size_t)(chunk * 8) * K + kt, (void*)(As + chunk * 512));
      gload_lds16(Wbase + (size_t)(chunk * 8) * K + kt, (void*)(Bs + chunk * 512));
    }
    __syncthreads();

    short8 af[4][2], bfr[4][2];
#pragma unroll
    for (int m = 0; m < 4; m++) {
      int row = wr * 64 + m * 16 + (lane & 15);
#pragma unroll
      for (int s = 0; s < 2; s++) {
        int slot = s * 4 + (lane >> 4);
        af[m][s] = *(const short8*)(As + row * 64 + ((slot ^ (row & 7)) * 8));
      }
    }
#pragma unroll
    for (int n = 0; n < 4; n++) {
      int row = wc * 64 + n * 16 + (lane & 15);
#pragma unroll
      for (int s = 0; s < 2; s++) {
        int slot = s * 4 + (lane >> 4);
        bfr[n][s] = *(const short8*)(Bs + row * 64 + ((slot ^ (row & 7)) * 8));
      }
    }
#pragma unroll
    for (int m = 0; m < 4; m++)
#pragma unroll
      for (int n = 0; n < 4; n++) {
        acc[m][n] = __builtin_amdgcn_mfma_f32_16x16x32_bf16(af[m][0], bfr[n][0], acc[m][n], 0, 0, 0);
        acc[m][n] = __builtin_amdgcn_mfma_f32_16x16x32_bf16(af[m][1], bfr[n][1], acc[m][n], 0, 0, 0);
      }
  }

  // epilogue: C/D layout col = lane&15, row = (lane>>4)*4 + i
#pragma unroll
  for (int m = 0; m < 4; m++) {
#pragma unroll
    for (int n = 0; n < 4; n++) {
      int r0 = bm + wr * 64 + m * 16 + (lane >> 4) * 4;
      int c = bn + wc * 64 + n * 16 + (lane & 15);
#pragma unroll
      for (int i = 0; i < 4; i++) {
        int r = r0 + i;
        float v = acc[m][n][i];
        if constexpr (EPI == 0) {
          ((u16t*)Cout)[(size_t)r * N + c] = f2bf(v);
        } else if constexpr (EPI == 1) {
          ((float*)Cout)[(size_t)r * N + c] = v + bias[c] + res[(size_t)r * N + c];
        } else {
          v += bias[c];
          float gl = 0.5f * v * (1.0f + erff(v * 0.70710678118f));
          ((u16t*)Cout)[(size_t)r * N + c] = f2bf(gl);
        }
      }
    }
  }
}

// ---------- fused flash attention ----------
// qkv: [B*N, 2304] bf16 (q|k|v interleaved by 768-chunks, head-major inside)
// ctx: [B*N, 768] bf16
// grid: (B*H = 96, N/64 = 16), 256 threads, wave w owns q-rows [qt + w*16, +16)
__global__ __launch_bounds__(256, 2) void attn_kernel(const u16t* __restrict__ qkv,
                                                      u16t* __restrict__ ctx) {
  __shared__ __align__(16) u16t Ks[64 * 64];     // swizzled K tile
  __shared__ __align__(16) u16t Vt[64 * 72];     // V^T, stride 72 (16B aligned rows)
  __shared__ __align__(16) u16t Ps[4][16 * 72];  // per-wave P
  int tid = threadIdx.x;
  int wave = tid >> 6, lane = tid & 63;
  int b = blockIdx.x / 12, h = blockIdx.x % 12;
  int qt = blockIdx.y * 64;
  const u16t* base = qkv + (size_t)b * 1024 * 2304 + h * 64;

  // Q fragments (A-layout): row = lane&15, k(d) = (lane>>4)*8 (+32 for second)
  int qrow = qt + wave * 16 + (lane & 15);
  const u16t* qp = base + (size_t)qrow * 2304 + (lane >> 4) * 8;
  short8 aq0 = *(const short8*)qp;
  short8 aq1 = *(const short8*)(qp + 32);

  const u16t* kbase = base + 768;
  const u16t* vbase = base + 1536;
  int lr = lane >> 3, lc = lane & 7;
  const u16t* kst = kbase + (size_t)lr * 2304 + ((lc ^ lr) * 8);   // swizzled src
  const u16t* vst = vbase + (size_t)lane * 2304 + wave * 16;

  float m_i[4] = {-1e30f, -1e30f, -1e30f, -1e30f};
  float l_i[4] = {0.f, 0.f, 0.f, 0.f};
  f32x4 o[4] = {};
  const float scale = 0.125f;  // 1/sqrt(64)
  u16t* Pw = Ps[wave];

  for (int kt = 0; kt < 1024; kt += 64) {
    __syncthreads();
    // stage K tile (64x64) via global_load_lds, 8 chunks of 8 rows
#pragma unroll
    for (int i = 0; i < 2; i++) {
      int chunk = wave * 2 + i;
      gload_lds16(kst + (size_t)(kt + chunk * 8) * 2304, (void*)(Ks + chunk * 512));
    }
    // stage V transposed: lane = k-row, wave owns d-chunk [wave*16, +16)
    {
      const u16t* vp = vst + (size_t)kt * 2304;
      union { uint4 u; u16t e[8]; } v0u, v1u;
      v0u.u = *(const uint4*)vp;
      v1u.u = *(const uint4*)(vp + 8);
#pragma unroll
      for (int j = 0; j < 8; j++) Vt[(wave * 16 + j) * 72 + lane] = v0u.e[j];
#pragma unroll
      for (int j = 0; j < 8; j++) Vt[(wave * 16 + 8 + j) * 72 + lane] = v1u.e[j];
    }
    __syncthreads();

    // S = Q K^T  (16 q x 64 k per wave)
    f32x4 s[4] = {};
#pragma unroll
    for (int n = 0; n < 4; n++) {
      int row = n * 16 + (lane & 15);
      int s0 = (lane >> 4);
      short8 bk0 = *(const short8*)(Ks + row * 64 + ((s0 ^ (row & 7)) * 8));
      short8 bk1 = *(const short8*)(Ks + row * 64 + (((s0 + 4) ^ (row & 7)) * 8));
      s[n] = __builtin_amdgcn_mfma_f32_16x16x32_bf16(aq0, bk0, s[n], 0, 0, 0);
      s[n] = __builtin_amdgcn_mfma_f32_16x16x32_bf16(aq1, bk1, s[n], 0, 0, 0);
    }

    // online softmax (row r = (lane>>4)*4+i, reduce over 16 lanes of the group)
    float alpha[4];
#pragma unroll
    for (int i = 0; i < 4; i++) {
      float mt = fmaxf(fmaxf(s[0][i], s[1][i]), fmaxf(s[2][i], s[3][i]));
      mt = fmaxf(mt, __shfl_xor(mt, 1, 64));
      mt = fmaxf(mt, __shfl_xor(mt, 2, 64));
      mt = fmaxf(mt, __shfl_xor(mt, 4, 64));
      mt = fmaxf(mt, __shfl_xor(mt, 8, 64));
      float mnew = fmaxf(m_i[i], mt * scale);
      alpha[i] = __expf(m_i[i] - mnew);
      m_i[i] = mnew;
    }
    float rsum[4] = {0.f, 0.f, 0.f, 0.f};
#pragma unroll
    for (int n = 0; n < 4; n++)
#pragma unroll
      for (int i = 0; i < 4; i++) {
        float p = __expf(s[n][i] * scale - m_i[i]);
        s[n][i] = p;
        rsum[i] += p;
      }
#pragma unroll
    for (int i = 0; i < 4; i++) {
      rsum[i] += __shfl_xor(rsum[i], 1, 64);
      rsum[i] += __shfl_xor(rsum[i], 2, 64);
      rsum[i] += __shfl_xor(rsum[i], 4, 64);
      rsum[i] += __shfl_xor(rsum[i], 8, 64);
      l_i[i] = l_i[i] * alpha[i] + rsum[i];
    }
    // P -> LDS (bf16, A-layout friendly row-major [16][72])
#pragma unroll
    for (int n = 0; n < 4; n++)
#pragma unroll
      for (int i = 0; i < 4; i++)
        Pw[((lane >> 4) * 4 + i) * 72 + n * 16 + (lane & 15)] = f2bf(s[n][i]);
    // rescale O
#pragma unroll
    for (int nd = 0; nd < 4; nd++)
#pragma unroll
      for (int i = 0; i < 4; i++) o[nd][i] *= alpha[i];
    // O += P @ V
#pragma unroll
    for (int st = 0; st < 2; st++) {
      short8 ap = *(const short8*)(Pw + (lane & 15) * 72 + st * 32 + (lane >> 4) * 8);
#pragma unroll
      for (int nd = 0; nd < 4; nd++) {
        short8 bv = *(const short8*)(Vt + (nd * 16 + (lane & 15)) * 72 + st * 32 + (lane >> 4) * 8);
        o[nd] = __builtin_amdgcn_mfma_f32_16x16x32_bf16(ap, bv, o[nd], 0, 0, 0);
      }
    }
  }

#pragma unroll
  for (int i = 0; i < 4; i++) l_i[i] = 1.0f / l_i[i];
  int q0 = qt + wave * 16 + (lane >> 4) * 4;
#pragma unroll
  for (int i = 0; i < 4; i++) {
    u16t* crow = ctx + (size_t)(b * 1024 + q0 + i) * 768 + h * 64;
#pragma unroll
    for (int nd = 0; nd < 4; nd++)
      crow[nd * 16 + (lane & 15)] = f2bf(o[nd][i] * l_i[i]);
  }
}

// ---------- launch ----------
extern "C" void kernel_launch(void* const* d_in, const int* in_sizes, int n_in,
                              void* d_out, int out_size, void* d_ws, size_t ws_size,
                              hipStream_t stream) {
  const float* x      = (const float*)d_in[0];
  const float* ln1_g  = (const float*)d_in[1];
  const float* ln1_b  = (const float*)d_in[2];
  const float* qkv_w  = (const float*)d_in[3];
  const float* proj_w = (const float*)d_in[4];
  const float* proj_b = (const float*)d_in[5];
  const float* ln2_g  = (const float*)d_in[6];
  const float* ln2_b  = (const float*)d_in[7];
  const float* fc1_w  = (const float*)d_in[8];
  const float* fc1_b  = (const float*)d_in[9];
  const float* fc2_w  = (const float*)d_in[10];
  const float* fc2_b  = (const float*)d_in[11];

  char* ws = (char*)d_ws;
  u16t* h1   = (u16t*)(ws + 0);           // 8192x768 bf16 (reused for ln2 out)
  u16t* qkvb = (u16t*)(ws + 12582912);    // 8192x2304 bf16
  u16t* ctx  = (u16t*)(ws + 50331648);    // 8192x768 bf16
  float* x2  = (float*)(ws + 62914560);   // 8192x768 f32
  u16t* hid  = (u16t*)(ws + 88080384);    // 8192x3072 bf16
  u16t* wq   = (u16t*)(ws + 138412032);   // 2304x768 bf16
  u16t* wp   = (u16t*)(ws + 141950976);   // 768x768 bf16
  u16t* w1   = (u16t*)(ws + 143130624);   // 3072x768 bf16
  u16t* w2   = (u16t*)(ws + 147849216);   // 768x3072 bf16
  float* out = (float*)d_out;

  cvt_bf16_kernel<<<864, 256, 0, stream>>>(qkv_w, wq, 221184);
  cvt_bf16_kernel<<<288, 256, 0, stream>>>(proj_w, wp, 73728);
  cvt_bf16_kernel<<<1152, 256, 0, stream>>>(fc1_w, w1, 294912);
  cvt_bf16_kernel<<<1152, 256, 0, stream>>>(fc2_w, w2, 294912);

  ln_kernel<<<8192, 256, 0, stream>>>(x, ln1_g, ln1_b, h1);
  gemm_bt<0><<<dim3(18, 64), 256, 0, stream>>>(h1, wq, qkvb, nullptr, nullptr, 8192, 2304, 768);
  attn_kernel<<<dim3(96, 16), 256, 0, stream>>>(qkvb, ctx);
  gemm_bt<1><<<dim3(6, 64), 256, 0, stream>>>(ctx, wp, x2, proj_b, x, 8192, 768, 768);
  ln_kernel<<<8192, 256, 0, stream>>>(x2, ln2_g, ln2_b, h1);
  gemm_bt<2><<<dim3(24, 64), 256, 0, stream>>>(h1, w1, hid, fc1_b, nullptr, 8192, 3072, 768);
  gemm_bt<1><<<dim3(6, 64), 256, 0, stream>>>(hid, w2, out, fc2_b, x2, 8192, 768, 3072);
}

// Round 2
// 305.885 us; speedup vs baseline: 1.0072x; 1.0072x over previous
//
#include <hip/hip_runtime.h>
#include <cstdint>

typedef __attribute__((ext_vector_type(8))) short short8;
typedef __attribute__((ext_vector_type(4))) float f32x4;
typedef unsigned short u16t;

// ---------- helpers ----------
__device__ __forceinline__ u16t f2bf(float f) {
  uint32_t u = __float_as_uint(f);
  u += 0x7fffu + ((u >> 16) & 1u);   // RNE
  return (u16t)(u >> 16);
}

__device__ __forceinline__ void gload_lds16(const void* g, void* l) {
  __builtin_amdgcn_global_load_lds(
      (const __attribute__((address_space(1))) void*)g,
      (__attribute__((address_space(3))) void*)l, 16, 0, 0);
}

// ---------- f32 -> bf16 convert ----------
__global__ __launch_bounds__(256) void cvt_bf16_kernel(const float* __restrict__ in,
                                                       u16t* __restrict__ out, int n8) {
  int i = blockIdx.x * 256 + threadIdx.x;
  if (i >= n8) return;
  const float4* p = (const float4*)in + (size_t)i * 2;
  float4 a = p[0], b = p[1];
  union { short8 v; u16t e[8]; } r;
  r.e[0] = f2bf(a.x); r.e[1] = f2bf(a.y); r.e[2] = f2bf(a.z); r.e[3] = f2bf(a.w);
  r.e[4] = f2bf(b.x); r.e[5] = f2bf(b.y); r.e[6] = f2bf(b.z); r.e[7] = f2bf(b.w);
  *((short8*)out + i) = r.v;
}

// ---------- LayerNorm (row = 768 f32) -> bf16 ----------
__global__ __launch_bounds__(256) void ln_kernel(const float* __restrict__ x,
                                                 const float* __restrict__ g,
                                                 const float* __restrict__ b,
                                                 u16t* __restrict__ out) {
  int row = blockIdx.x, tid = threadIdx.x;
  int wave = tid >> 6, lane = tid & 63;
  const float* xr = x + (size_t)row * 768;
  float v0 = xr[tid], v1 = xr[tid + 256], v2 = xr[tid + 512];
  float s = v0 + v1 + v2;
  float q = v0 * v0 + v1 * v1 + v2 * v2;
#pragma unroll
  for (int m = 32; m >= 1; m >>= 1) {
    s += __shfl_xor(s, m, 64);
    q += __shfl_xor(q, m, 64);
  }
  __shared__ float red[8];
  if (lane == 0) { red[wave] = s; red[4 + wave] = q; }
  __syncthreads();
  s = red[0] + red[1] + red[2] + red[3];
  q = red[4] + red[5] + red[6] + red[7];
  float mu = s * (1.0f / 768.0f);
  float var = q * (1.0f / 768.0f) - mu * mu;
  float rs = rsqrtf(var + 1e-5f);
  u16t* orow = out + (size_t)row * 768;
  orow[tid]       = f2bf((v0 - mu) * rs * g[tid]       + b[tid]);
  orow[tid + 256] = f2bf((v1 - mu) * rs * g[tid + 256] + b[tid + 256]);
  orow[tid + 512] = f2bf((v2 - mu) * rs * g[tid + 512] + b[tid + 512]);
}

// ---------- GEMM: C[M,N] = A[M,K] @ W[N,K]^T  (bf16 in, fp32 acc) ----------
// EPI 0: bf16 store of acc
// EPI 1: f32 store of acc + bias[c] + res[r*N+c]
// EPI 2: bf16 store of gelu_exact(acc + bias[c])
// BM: 128 or 64 rows per block (BN fixed at 128)
template <int EPI, int BM>
__global__ __launch_bounds__(256, 2) void gemm_bt(const u16t* __restrict__ A,
                                                  const u16t* __restrict__ W,
                                                  void* __restrict__ Cout,
                                                  const float* __restrict__ bias,
                                                  const float* __restrict__ res,
                                                  int M, int N, int K) {
  __shared__ __align__(16) u16t As[BM * 64];
  __shared__ __align__(16) u16t Bs[128 * 64];
  constexpr int MF = BM / 32;   // m-fragments per wave
  int tid = threadIdx.x;
  int wave = tid >> 6, lane = tid & 63;
  int wr = wave >> 1, wc = wave & 1;
  int bm = blockIdx.y * BM;
  int bn = blockIdx.x * 128;
  f32x4 acc[MF][4] = {};

  int lr = lane >> 3;            // staging row-in-chunk 0..7
  int lc = lane & 7;             // staging 16B slot 0..7
  int srcslot = lc ^ lr;         // inverse-swizzled source slot
  const u16t* Abase = A + (size_t)(bm + lr) * K + srcslot * 8;
  const u16t* Wbase = W + (size_t)(bn + lr) * K + srcslot * 8;

  for (int kt = 0; kt < K; kt += 64) {
    __syncthreads();
#pragma unroll
    for (int i = 0; i < BM / 32; i++) {
      int chunk = wave * (BM / 32) + i;  // BM/8 chunks of 8 rows x 128B
      gload_lds16(Abase + (size_t)(chunk * 8) * K + kt, (void*)(As + chunk * 512));
    }
#pragma unroll
    for (int i = 0; i < 4; i++) {
      int chunk = wave * 4 + i;
      gload_lds16(Wbase + (size_t)(chunk * 8) * K + kt, (void*)(Bs + chunk * 512));
    }
    __syncthreads();

    short8 af[MF][2], bfr[4][2];
#pragma unroll
    for (int m = 0; m < MF; m++) {
      int row = wr * (BM / 2) + m * 16 + (lane & 15);
#pragma unroll
      for (int s = 0; s < 2; s++) {
        int slot = s * 4 + (lane >> 4);
        af[m][s] = *(const short8*)(As + row * 64 + ((slot ^ (row & 7)) * 8));
      }
    }
#pragma unroll
    for (int n = 0; n < 4; n++) {
      int row = wc * 64 + n * 16 + (lane & 15);
#pragma unroll
      for (int s = 0; s < 2; s++) {
        int slot = s * 4 + (lane >> 4);
        bfr[n][s] = *(const short8*)(Bs + row * 64 + ((slot ^ (row & 7)) * 8));
      }
    }
    __builtin_amdgcn_s_setprio(1);
#pragma unroll
    for (int m = 0; m < MF; m++)
#pragma unroll
      for (int n = 0; n < 4; n++) {
        acc[m][n] = __builtin_amdgcn_mfma_f32_16x16x32_bf16(af[m][0], bfr[n][0], acc[m][n], 0, 0, 0);
        acc[m][n] = __builtin_amdgcn_mfma_f32_16x16x32_bf16(af[m][1], bfr[n][1], acc[m][n], 0, 0, 0);
      }
    __builtin_amdgcn_s_setprio(0);
  }

  // epilogue: C/D layout col = lane&15, row = (lane>>4)*4 + i
#pragma unroll
  for (int m = 0; m < MF; m++) {
#pragma unroll
    for (int n = 0; n < 4; n++) {
      int r0 = bm + wr * (BM / 2) + m * 16 + (lane >> 4) * 4;
      int c = bn + wc * 64 + n * 16 + (lane & 15);
#pragma unroll
      for (int i = 0; i < 4; i++) {
        int r = r0 + i;
        float v = acc[m][n][i];
        if constexpr (EPI == 0) {
          ((u16t*)Cout)[(size_t)r * N + c] = f2bf(v);
        } else if constexpr (EPI == 1) {
          ((float*)Cout)[(size_t)r * N + c] = v + bias[c] + res[(size_t)r * N + c];
        } else {
          v += bias[c];
          float gl = 0.5f * v * (1.0f + erff(v * 0.70710678118f));
          ((u16t*)Cout)[(size_t)r * N + c] = f2bf(gl);
        }
      }
    }
  }
}

// ---------- fused flash attention (2-phase pipelined) ----------
// qkv: [B*N, 2304] bf16; ctx: [B*N, 768] bf16
// grid: (B*H = 96, N/64 = 16), 256 threads, wave w owns q-rows [qt + w*16, +16)
__global__ __launch_bounds__(256, 2) void attn_kernel(const u16t* __restrict__ qkv,
                                                      u16t* __restrict__ ctx) {
  __shared__ __align__(16) u16t Ks[2][64 * 64];   // swizzled K tiles (double-buffered)
  __shared__ __align__(16) u16t Vt[2][64 * 72];   // V^T tiles (double-buffered)
  __shared__ __align__(16) u16t Ps[4][16 * 72];   // per-wave P
  int tid = threadIdx.x;
  int wave = tid >> 6, lane = tid & 63;
  int b = blockIdx.x / 12, h = blockIdx.x % 12;
  int qt = blockIdx.y * 64;
  const u16t* base = qkv + (size_t)b * 1024 * 2304 + h * 64;

  // Q fragments (A-layout): row = lane&15, k(d) = (lane>>4)*8 (+32 for second)
  int qrow = qt + wave * 16 + (lane & 15);
  const u16t* qp = base + (size_t)qrow * 2304 + (lane >> 4) * 8;
  short8 aq0 = *(const short8*)qp;
  short8 aq1 = *(const short8*)(qp + 32);

  const u16t* kbase = base + 768;
  const u16t* vbase = base + 1536;
  int lr = lane >> 3, lc = lane & 7;
  const u16t* kst = kbase + (size_t)lr * 2304 + ((lc ^ lr) * 8);   // swizzled src
  const u16t* vst = vbase + (size_t)lane * 2304 + wave * 16;

  float m_i[4] = {-1e30f, -1e30f, -1e30f, -1e30f};
  float l_i[4] = {0.f, 0.f, 0.f, 0.f};
  f32x4 o[4] = {};
  const float scale = 0.125f;  // 1/sqrt(64)
  u16t* Pw = Ps[wave];

  union { uint4 u; u16t e[8]; } v0u, v1u;

  auto loadV = [&](int kt) {
    const u16t* vp = vst + (size_t)kt * 2304;
    v0u.u = *(const uint4*)vp;
    v1u.u = *(const uint4*)(vp + 8);
  };
  auto stageK = [&](int kt, int buf) {
#pragma unroll
    for (int i = 0; i < 2; i++) {
      int chunk = wave * 2 + i;
      gload_lds16(kst + (size_t)(kt + chunk * 8) * 2304, (void*)(Ks[buf] + chunk * 512));
    }
  };
  auto writeV = [&](int buf) {
#pragma unroll
    for (int j = 0; j < 8; j++) Vt[buf][(wave * 16 + j) * 72 + lane] = v0u.e[j];
#pragma unroll
    for (int j = 0; j < 8; j++) Vt[buf][(wave * 16 + 8 + j) * 72 + lane] = v1u.e[j];
  };

  // prologue: stage tile 0
  loadV(0);
  stageK(0, 0);
  writeV(0);
  __syncthreads();

  for (int t = 0; t < 16; ++t) {
    int buf = t & 1;
    // issue next tile's loads before computing current (latency hides under compute)
    if (t < 15) {
      loadV((t + 1) * 64);
      stageK((t + 1) * 64, buf ^ 1);
    }

    // S = Q K^T  (16 q x 64 k per wave)
    const u16t* Kb = Ks[buf];
    f32x4 s[4] = {};
    __builtin_amdgcn_s_setprio(1);
#pragma unroll
    for (int n = 0; n < 4; n++) {
      int row = n * 16 + (lane & 15);
      int s0 = (lane >> 4);
      short8 bk0 = *(const short8*)(Kb + row * 64 + ((s0 ^ (row & 7)) * 8));
      short8 bk1 = *(const short8*)(Kb + row * 64 + (((s0 + 4) ^ (row & 7)) * 8));
      s[n] = __builtin_amdgcn_mfma_f32_16x16x32_bf16(aq0, bk0, s[n], 0, 0, 0);
      s[n] = __builtin_amdgcn_mfma_f32_16x16x32_bf16(aq1, bk1, s[n], 0, 0, 0);
    }
    __builtin_amdgcn_s_setprio(0);

    // online softmax (row r = (lane>>4)*4+i, reduce over 16 lanes of the group)
    float alpha[4];
#pragma unroll
    for (int i = 0; i < 4; i++) {
      float mt = fmaxf(fmaxf(s[0][i], s[1][i]), fmaxf(s[2][i], s[3][i]));
      mt = fmaxf(mt, __shfl_xor(mt, 1, 64));
      mt = fmaxf(mt, __shfl_xor(mt, 2, 64));
      mt = fmaxf(mt, __shfl_xor(mt, 4, 64));
      mt = fmaxf(mt, __shfl_xor(mt, 8, 64));
      float mnew = fmaxf(m_i[i], mt * scale);
      alpha[i] = __expf(m_i[i] - mnew);
      m_i[i] = mnew;
    }
    float rsum[4] = {0.f, 0.f, 0.f, 0.f};
#pragma unroll
    for (int n = 0; n < 4; n++)
#pragma unroll
      for (int i = 0; i < 4; i++) {
        float p = __expf(s[n][i] * scale - m_i[i]);
        s[n][i] = p;
        rsum[i] += p;
      }
#pragma unroll
    for (int i = 0; i < 4; i++) {
      rsum[i] += __shfl_xor(rsum[i], 1, 64);
      rsum[i] += __shfl_xor(rsum[i], 2, 64);
      rsum[i] += __shfl_xor(rsum[i], 4, 64);
      rsum[i] += __shfl_xor(rsum[i], 8, 64);
      l_i[i] = l_i[i] * alpha[i] + rsum[i];
    }
    // P -> LDS (bf16, A-layout friendly row-major [16][72])
#pragma unroll
    for (int n = 0; n < 4; n++)
#pragma unroll
      for (int i = 0; i < 4; i++)
        Pw[((lane >> 4) * 4 + i) * 72 + n * 16 + (lane & 15)] = f2bf(s[n][i]);
    // rescale O
#pragma unroll
    for (int nd = 0; nd < 4; nd++)
#pragma unroll
      for (int i = 0; i < 4; i++) o[nd][i] *= alpha[i];
    // O += P @ V
    const u16t* Vb = Vt[buf];
    __builtin_amdgcn_s_setprio(1);
#pragma unroll
    for (int st = 0; st < 2; st++) {
      short8 ap = *(const short8*)(Pw + (lane & 15) * 72 + st * 32 + (lane >> 4) * 8);
#pragma unroll
      for (int nd = 0; nd < 4; nd++) {
        short8 bv = *(const short8*)(Vb + (nd * 16 + (lane & 15)) * 72 + st * 32 + (lane >> 4) * 8);
        o[nd] = __builtin_amdgcn_mfma_f32_16x16x32_bf16(ap, bv, o[nd], 0, 0, 0);
      }
    }
    __builtin_amdgcn_s_setprio(0);

    // land next tile's V into the other buffer (compiler waits vmcnt for v regs)
    if (t < 15) writeV(buf ^ 1);
    __syncthreads();
  }

#pragma unroll
  for (int i = 0; i < 4; i++) l_i[i] = 1.0f / l_i[i];
  int q0 = qt + wave * 16 + (lane >> 4) * 4;
#pragma unroll
  for (int i = 0; i < 4; i++) {
    u16t* crow = ctx + (size_t)(b * 1024 + q0 + i) * 768 + h * 64;
#pragma unroll
    for (int nd = 0; nd < 4; nd++)
      crow[nd * 16 + (lane & 15)] = f2bf(o[nd][i] * l_i[i]);
  }
}

// ---------- launch ----------
extern "C" void kernel_launch(void* const* d_in, const int* in_sizes, int n_in,
                              void* d_out, int out_size, void* d_ws, size_t ws_size,
                              hipStream_t stream) {
  const float* x      = (const float*)d_in[0];
  const float* ln1_g  = (const float*)d_in[1];
  const float* ln1_b  = (const float*)d_in[2];
  const float* qkv_w  = (const float*)d_in[3];
  const float* proj_w = (const float*)d_in[4];
  const float* proj_b = (const float*)d_in[5];
  const float* ln2_g  = (const float*)d_in[6];
  const float* ln2_b  = (const float*)d_in[7];
  const float* fc1_w  = (const float*)d_in[8];
  const float* fc1_b  = (const float*)d_in[9];
  const float* fc2_w  = (const float*)d_in[10];
  const float* fc2_b  = (const float*)d_in[11];

  char* ws = (char*)d_ws;
  u16t* h1   = (u16t*)(ws + 0);           // 8192x768 bf16 (reused for ln2 out)
  u16t* qkvb = (u16t*)(ws + 12582912);    // 8192x2304 bf16
  u16t* ctx  = (u16t*)(ws + 50331648);    // 8192x768 bf16
  float* x2  = (float*)(ws + 62914560);   // 8192x768 f32
  u16t* hid  = (u16t*)(ws + 88080384);    // 8192x3072 bf16
  u16t* wq   = (u16t*)(ws + 138412032);   // 2304x768 bf16
  u16t* wp   = (u16t*)(ws + 141950976);   // 768x768 bf16
  u16t* w1   = (u16t*)(ws + 143130624);   // 3072x768 bf16
  u16t* w2   = (u16t*)(ws + 147849216);   // 768x3072 bf16
  float* out = (float*)d_out;

  cvt_bf16_kernel<<<864, 256, 0, stream>>>(qkv_w, wq, 221184);
  cvt_bf16_kernel<<<288, 256, 0, stream>>>(proj_w, wp, 73728);
  cvt_bf16_kernel<<<1152, 256, 0, stream>>>(fc1_w, w1, 294912);
  cvt_bf16_kernel<<<1152, 256, 0, stream>>>(fc2_w, w2, 294912);

  ln_kernel<<<8192, 256, 0, stream>>>(x, ln1_g, ln1_b, h1);
  gemm_bt<0, 128><<<dim3(18, 64), 256, 0, stream>>>(h1, wq, qkvb, nullptr, nullptr, 8192, 2304, 768);
  attn_kernel<<<dim3(96, 16), 256, 0, stream>>>(qkvb, ctx);
  gemm_bt<1, 64><<<dim3(6, 128), 256, 0, stream>>>(ctx, wp, x2, proj_b, x, 8192, 768, 768);
  ln_kernel<<<8192, 256, 0, stream>>>(x2, ln2_g, ln2_b, h1);
  gemm_bt<2, 128><<<dim3(24, 64), 256, 0, stream>>>(h1, w1, hid, fc1_b, nullptr, 8192, 3072, 768);
  gemm_bt<1, 64><<<dim3(6, 128), 256, 0, stream>>>(hid, w2, out, fc2_b, x2, 8192, 768, 3072);
}